// Round 13
// baseline (653.115 us; speedup 1.0000x reference)
//
#include <hip/hip_runtime.h>

typedef unsigned short u16;
typedef unsigned int u32;
typedef unsigned char u8;
typedef __attribute__((ext_vector_type(4))) int int4v;
typedef __attribute__((ext_vector_type(8))) int int8v;
typedef __attribute__((ext_vector_type(4))) float f32x4;

#define NEG (-1e30f)
#define LN2 0.6931471805599453f
#define INV_LN2 1.4426950408889634f

// Problem sizes
#define B_N 16
#define T_N 500
#define E_N 1024
#define V_N 4000
#define L_N 100
#define M_P 8064     // 63*128 padded rows
#define N_P 4096     // 32*128 padded vocab

// ws layout (bytes)
#define OFF_A   0UL          // fp8 A  [8064][1024]   = 8,257,536
#define OFF_B   8257536UL    // fp8 Bt [4096][1024]   = 4,194,304
#define OFF_P   12451840UL   // f32 partial [8064][64] = 2,064,384
#define OFF_LR  14516224UL   // f32 labraw [16][500][104] = 3,328,000 (end ~17.8 MB)

__device__ __forceinline__ u16 f2bf(float f) {
  u32 u = __float_as_uint(f);
  u += 0x7fffu + ((u >> 16) & 1u);   // RNE
  return (u16)(u >> 16);
}
__device__ __forceinline__ float bf2f(u16 h) {
  return __uint_as_float(((u32)h) << 16);
}
__device__ __forceinline__ void gl_lds16(const void* g, void* l) {
  __builtin_amdgcn_global_load_lds((const __attribute__((address_space(1))) void*)g,
                                   (__attribute__((address_space(3))) void*)l, 16, 0, 0);
}
// DPP helpers: ctrl must be an ICE -> template parameter.
template <int CTRL>
__device__ __forceinline__ float dpp_f(float x, float fill) {
  return __int_as_float(__builtin_amdgcn_update_dpp(
      __float_as_int(fill), __float_as_int(x), CTRL, 0xF, 0xF, false));
}
__device__ __forceinline__ float dpp_shr1(float x, float fill) {
  return dpp_f<0x138>(x, fill);   // wf_shr1: lane L <- L-1; lane 0 takes fill
}
// wave max -> valid in lane 63. fill = identity.
__device__ __forceinline__ float wave_max(float x, float fill) {
  x = fmaxf(x, dpp_f<0x111>(x, fill));
  x = fmaxf(x, dpp_f<0x112>(x, fill));
  x = fmaxf(x, dpp_f<0x114>(x, fill));
  x = fmaxf(x, dpp_f<0x118>(x, fill));
  x = fmaxf(x, dpp_f<0x142>(x, fill));   // row_bcast:15
  x = fmaxf(x, dpp_f<0x143>(x, fill));   // row_bcast:31
  return x;
}
// wave sum -> valid in lane 63.
__device__ __forceinline__ float wave_sum(float x) {
  x += dpp_f<0x111>(x, 0.f); x += dpp_f<0x112>(x, 0.f);
  x += dpp_f<0x114>(x, 0.f); x += dpp_f<0x118>(x, 0.f);
  x += dpp_f<0x142>(x, 0.f); x += dpp_f<0x143>(x, 0.f);
  return x;
}

// K1: fused input casts. Blocks [0,8064): hs f32 -> fp8 A (pad rows 0), zero d_out.
// Blocks [8064,12160): W transpose-cast -> fp8 Bt, pre-scaled x64.
__global__ __launch_bounds__(256) void castAB(const float* __restrict__ hs,
                                              const float* __restrict__ W,
                                              u32* __restrict__ Aq,
                                              u8* __restrict__ Bq,
                                              float* __restrict__ out) {
  __shared__ float tile[32][33];
  if (blockIdx.x < 8064) {
    int idx = blockIdx.x * 256 + threadIdx.x;   // float4 groups
    if (idx == 0) out[0] = 0.f;
    int row = idx >> 8;
    float4 x;
    if (row < B_N * T_N) x = ((const float4*)hs)[idx];
    else x = make_float4(0.f, 0.f, 0.f, 0.f);
    u32 p = __builtin_amdgcn_cvt_pk_fp8_f32(x.x, x.y, 0, false);
    p = __builtin_amdgcn_cvt_pk_fp8_f32(x.z, x.w, p, true);
    Aq[idx] = p;
  } else {
    int bid = blockIdx.x - 8064;                // 0..4095 = (128 N) x (32 E)
    int v0 = (bid & 127) * 32;
    int e0 = (bid >> 7) * 32;
    int tx = threadIdx.x & 31, ty = threadIdx.x >> 5;
#pragma unroll
    for (int i = 0; i < 4; ++i) {
      int e = e0 + ty * 4 + i;
      int v = v0 + tx;
      tile[ty * 4 + i][tx] = (v < V_N) ? W[e * V_N + v] : 0.f;
    }
    __syncthreads();
#pragma unroll
    for (int i = 0; i < 4; ++i) {
      int vloc = ty * 4 + i;
      float x = tile[tx][vloc] * 64.f;
      u32 p = __builtin_amdgcn_cvt_pk_fp8_f32(x, x, 0, false);
      Bq[(size_t)(v0 + vloc) * 1024 + (e0 + tx)] = (u8)(p & 0xff);
    }
  }
}

// K2: MX-fp8 GEMM, fused epilogue, C never materialized.
// launch_bounds(256,3): VGPR cap ~168 -> 3 blocks/CU. (256,2)=128 spills the
// K-loop (R10/R11: 368 MB scratch); unconstrained (256) allocates 188 ->
// 2 blocks/CU, latency-bound (R12: MfmaUtil 7%). The epilogue is fully
// LDS-based: acc[i] is dumped chunk-by-chunk and DIES -- no epilogue state
// is register-live across the K-loop or the chunk loop.
__global__ __launch_bounds__(256, 3) void gemm_fp8(const u8* __restrict__ A,
                                                   const u8* __restrict__ Bq,
                                                   const float* __restrict__ bias,
                                                   const int* __restrict__ ys,
                                                   float* __restrict__ partial,
                                                   float* __restrict__ labraw) {
  __shared__ __align__(16) u8 smem[33792];     // As(16896)+Bs(16896); epilogue: stage f32[32][132]
  __shared__ int extL2[2][104];
  u8* As = smem;
  u8* Bs = smem + 16896;
  float* stage = (float*)smem;                 // 32*132*4 = 16896 B
  const int tid = threadIdx.x;
  const int lane = tid & 63;
  const int w = tid >> 6;
  const int wm = w >> 1, wn = w & 1;
  const size_t m0 = (size_t)blockIdx.y * 128;
  const size_t n0 = (size_t)blockIdx.x * 128;

  const int b0 = (int)m0 / 500;
  const int b1 = min((int)m0 + 127, B_N * T_N - 1) / 500;
  if (tid < 101)
    extL2[0][tid] = (tid == 0) ? 0 : max(ys[b0 * L_N + tid - 1], 0);
  else if (tid >= 128 && tid < 229) {
    int t2 = tid - 128;
    extL2[1][t2] = (t2 == 0) ? 0 : max(ys[b1 * L_N + t2 - 1], 0);
  }

  const int lr = lane >> 3;
  const int lc = lane & 7;
  const int gc = lc ^ lr;          // XOR-swizzled global chunk
  const u8* gA = A + (m0 + w * 32 + lr) * 1024 + gc * 16;
  const u8* gB = Bq + (n0 + w * 32 + lr) * 1024 + gc * 16;
  u8* sA = As + (w * 4) * 1056;
  u8* sB = Bs + (w * 4) * 1056;

  f32x4 acc[4][4];
#pragma unroll
  for (int i = 0; i < 4; ++i)
#pragma unroll
    for (int j = 0; j < 4; ++j) acc[i][j] = (f32x4){0.f, 0.f, 0.f, 0.f};

  const int fr = lane & 15, q = lane >> 4;
  const int c0 = ((2 * q) ^ (fr & 7)) * 16;
  const int c1 = ((2 * q + 1) ^ (fr & 7)) * 16;
  const int rA0 = wm * 64 + fr;
  const int rB0 = wn * 64 + fr;

  for (int kt = 0; kt < 1024; kt += 128) {
#pragma unroll
    for (int u = 0; u < 4; ++u) {
      gl_lds16(gA + (size_t)u * 8192 + kt, sA + u * 1056);
      gl_lds16(gB + (size_t)u * 8192 + kt, sB + u * 1056);
    }
    __syncthreads();
    int8v af[4], bf[4];
#pragma unroll
    for (int i = 0; i < 4; ++i) {
      int r = rA0 + i * 16;
      const u8* p = As + (r >> 3) * 1056 + (r & 7) * 128;
      int4v lo = *(const int4v*)(p + c0);
      int4v hi = *(const int4v*)(p + c1);
      af[i] = (int8v){lo[0], lo[1], lo[2], lo[3], hi[0], hi[1], hi[2], hi[3]};
    }
#pragma unroll
    for (int j = 0; j < 4; ++j) {
      int r = rB0 + j * 16;
      const u8* p = Bs + (r >> 3) * 1056 + (r & 7) * 128;
      int4v lo = *(const int4v*)(p + c0);
      int4v hi = *(const int4v*)(p + c1);
      bf[j] = (int8v){lo[0], lo[1], lo[2], lo[3], hi[0], hi[1], hi[2], hi[3]};
    }
#pragma unroll
    for (int i = 0; i < 4; ++i)
#pragma unroll
      for (int j = 0; j < 4; ++j)
        acc[i][j] = __builtin_amdgcn_mfma_scale_f32_16x16x128_f8f6f4(
            af[i], bf[j], acc[i][j], 0, 0,
            0, 0x7F7F7F7F, 0, 0x7F7F7F7F);   // E8M0 127 = 2^0
    __syncthreads();
  }

  // ---- fused epilogue: all work from LDS; acc dies chunk-by-chunk ----
  const int cq = lane >> 4, cc = lane & 15;
  const float K1C = 0.015625f * INV_LN2;     // undo W x64, to log2 domain
  // this thread's fixed 16 columns for the row-sum: h*64 + q4*16 .. +15
  const int rl = tid >> 3;                   // 0..31: row within a 32-row chunk
  const int h = (tid >> 2) & 1;              // column half (-> partial slice)
  const int q4 = tid & 3;                    // quarter within the half
  float b2[16];
  {
    const int cbase = (int)n0 + h * 64 + q4 * 16;
#pragma unroll
    for (int k = 0; k < 16; ++k)
      b2[k] = (cbase + k < V_N) ? bias[cbase + k] * INV_LN2 : -1e38f;  // pad -> exp2=0
  }

  for (int i = 0; i < 4; ++i) {
    __syncthreads();   // prior chunk's reads done (and K-loop LDS reuse safe)
#pragma unroll
    for (int j = 0; j < 4; ++j)
#pragma unroll
      for (int g = 0; g < 4; ++g)
        stage[(wm * 16 + cq * 4 + g) * 132 + wn * 64 + j * 16 + cc] = acc[i][j][g];
    __syncthreads();

    // (a) row sums: 16 exp2/thread from LDS, 4-lane DPP reduce (groups aligned)
    {
      const float4* rp4 = (const float4*)(stage + rl * 132 + h * 64 + q4 * 16);
      float s = 0.f;
#pragma unroll
      for (int kk = 0; kk < 4; ++kk) {
        float4 v = rp4[kk];
        s += exp2f(v.x * K1C + b2[4 * kk + 0]) + exp2f(v.y * K1C + b2[4 * kk + 1]) +
             exp2f(v.z * K1C + b2[4 * kk + 2]) + exp2f(v.w * K1C + b2[4 * kk + 3]);
      }
      s += dpp_f<0x111>(s, 0.f);   // lanes q4==3 accumulate their aligned group
      s += dpp_f<0x112>(s, 0.f);
      if (q4 == 3) {
        int row = (int)m0 + (rl >> 4) * 64 + i * 16 + (rl & 15);
        partial[(size_t)row * 64 + blockIdx.x * 2 + h] = s;
      }
    }

    // (b) label gather: 32 rows x 104 slots = 13 tasks/thread
    for (int task = tid; task < 32 * 104; task += 256) {
      int s = task % 104;
      int rr = task / 104;
      if (s <= 100) {
        int row = (int)m0 + (rr >> 4) * 64 + i * 16 + (rr & 15);
        if (row < B_N * T_N) {
          int bb = (row >= (b0 + 1) * 500) ? b1 : b0;
          int bi = (bb == b0) ? 0 : 1;
          int v = extL2[bi][s];
          int lo = v - (int)n0;
          if (lo >= 0 && lo < 128) {
            float val = stage[rr * 132 + lo];
            labraw[((size_t)bb * 500 + (row - bb * 500)) * 104 + s] =
                val * K1C + bias[v] * INV_LN2;
          }
        }
      }
    }
  }
}

// K3: finalize + CTC DP in one kernel (512 threads = 8 waves).
// Phase 1 (all waves): per row t, lse2 = log2(sum of 64 slice-partials);
// normalize 101 label z2's, max-normalize, exp2 -> P' tables built in LDS.
// Phase 2 (wave 0): linear-domain scaled-forward DP (verified R9..R12).
__global__ __launch_bounds__(512) void ctc_dp(const float* __restrict__ partial,
                                              const float* __restrict__ labraw,
                                              const int* __restrict__ ys,
                                              const int* __restrict__ ilens,
                                              const int* __restrict__ olens,
                                              float* __restrict__ out) {
  __shared__ __align__(16) u32 sP[500 * 64];   // 128000 B pair table
  __shared__ float sPB[512];
  __shared__ float sCT[512];
  __shared__ int extL[104];
  __shared__ float tmp[8][128];
  int b = blockIdx.x;
  int tid = threadIdx.x;
  int w = tid >> 6, L = tid & 63;

  if (tid < 101) extL[tid] = (tid == 0) ? 0 : max(ys[b * L_N + tid - 1], 0);

  const float* pbase = partial + (size_t)b * 500 * 64;
  const float* lbase = labraw + (size_t)b * 500 * 104;
  for (int t = w; t < T_N; t += 8) {
    float S = wave_sum(pbase[t * 64 + L]);
    float lse2 = __log2f(__int_as_float(
        __builtin_amdgcn_readlane(__float_as_int(S), 63)));
    float za = lbase[t * 104 + L] - lse2;                       // s = L
    float zb = (L < 37) ? lbase[t * 104 + 64 + L] - lse2 : NEG; // s = 64+L
    float m = wave_max(fmaxf(za, zb), NEG);
    float c = __int_as_float(__builtin_amdgcn_readlane(__float_as_int(m), 63));
    float pa = exp2f(za - c);
    float pb = (L < 37) ? exp2f(zb - c) : 0.f;
    tmp[w][L] = pa;
    if (L < 40) tmp[w][64 + L] = pb;     // s=101..103 get 0
    asm volatile("s_waitcnt lgkmcnt(0)" ::: "memory");   // in-wave LDS transpose
    float p0 = (L < 50) ? tmp[w][1 + 2 * L] : 0.f;
    float p1 = (L < 50) ? tmp[w][2 + 2 * L] : 0.f;
    sP[t * 64 + L] = ((u32)f2bf(p1) << 16) | (u32)f2bf(p0);
    if (L == 0) { sPB[t] = tmp[w][0]; sCT[t] = c; }
  }
  __syncthreads();
  if (w != 0) return;

  // ---- DP (wave 0 only) ----
  int k0 = 2 * L, k1 = 2 * L + 1;
  int y0 = extL[1 + min(k0, L_N - 1)];
  int y1 = extL[1 + min(k1, L_N - 1)];
  int y0m = (k0 > 0) ? extL[1 + min(k0 - 1, L_N - 1)] : -1;
  bool allow1 = (y0 != 0) && (y0 != y0m);
  bool allow3 = (y1 != 0) && (y1 != y0);
  int il = ilens[b];   // >= 250

  float a0 = 0.f, a1 = 0.f, a2 = 0.f, a3 = 0.f;
  {
    float pb0 = sPB[0];
    float a1v = bf2f((u16)(sP[0] & 0xffffu));
    if (L == 0) { a0 = pb0; a1 = a1v; }
  }
  int accE = 0;

  u32 curP[8]; float curB[8];
#pragma unroll
  for (int u = 0; u < 8; ++u) {
    curP[u] = sP[(1 + u) * 64 + L];
    curB[u] = sPB[1 + u];
  }
  for (int t0 = 1; t0 < il; t0 += 8) {
    u32 nP[8]; float nB[8];
#pragma unroll
    for (int u = 0; u < 8; ++u) {
      int tn = min(t0 + 8 + u, T_N - 1);
      nP[u] = sP[tn * 64 + L];
      nB[u] = sPB[tn];
    }
#pragma unroll
    for (int u = 0; u < 8; ++u) {
      int t = t0 + u;
      float pk0 = __uint_as_float((curP[u] & 0xffffu) << 16);
      float pk1 = __uint_as_float(curP[u] & 0xffff0000u);
      float p3 = dpp_shr1(a3, 0.f);
      float p3m = allow1 ? p3 : 0.f;
      float a1m = allow3 ? a1 : 0.f;
      float n0 = (a0 + p3) * curB[u];
      float n1 = (a1 + a0 + p3m) * pk0;
      float n2 = (a2 + a1) * curB[u];
      float n3 = (a3 + a2 + a1m) * pk1;
      bool live = t < il;
      a0 = live ? n0 : a0; a1 = live ? n1 : a1;
      a2 = live ? n2 : a2; a3 = live ? n3 : a3;
    }
    float m = fmaxf(fmaxf(a0, a1), fmaxf(a2, a3));
    m = wave_max(m, 0.f);
    u32 mb = (u32)__builtin_amdgcn_readlane(__float_as_int(m), 63);
    int ex = (int)((mb >> 23) & 0xffu);
    ex = (ex < 1) ? 1 : ex;
    float scale = __uint_as_float((u32)(254 - ex) << 23);   // 2^(127-ex)
    a0 *= scale; a1 *= scale; a2 *= scale; a3 *= scale;
    accE += ex - 127;
#pragma unroll
    for (int u = 0; u < 8; ++u) { curP[u] = nP[u]; curB[u] = nB[u]; }
  }

  float cs = 0.f;
#pragma unroll
  for (int i = 0; i < 8; ++i) {
    int t = L + 64 * i;
    cs += (t < il) ? sCT[t] : 0.f;
  }
  cs = wave_sum(cs);
  float csum = __int_as_float(__builtin_amdgcn_readlane(__float_as_int(cs), 63));

  int ol = olens[b];
  int s1 = 2 * ol, s2 = 2 * ol - 1;
  int j1 = s1 & 3, j2 = s2 & 3;
  float t1 = (j1 == 0) ? a0 : a2;
  float t2 = (j2 == 1) ? a1 : a3;
  float x1 = __shfl(t1, s1 >> 2);
  float x2 = __shfl(t2, s2 >> 2);
  float ll2 = __log2f(x1 + x2) + (float)accE + csum;
  if (L == 0) atomicAdd(out, -ll2 * LN2 * (1.0f / B_N));
}

extern "C" void kernel_launch(void* const* d_in, const int* in_sizes, int n_in,
                              void* d_out, int out_size, void* d_ws, size_t ws_size,
                              hipStream_t stream) {
  const float* hs    = (const float*)d_in[0];
  const float* W     = (const float*)d_in[1];
  const float* bias  = (const float*)d_in[2];
  const int*   ys    = (const int*)d_in[3];
  const int*   ilens = (const int*)d_in[4];
  const int*   olens = (const int*)d_in[5];
  char* ws = (char*)d_ws;
  u8*    Aq   = (u8*)(ws + OFF_A);
  u8*    Bq   = (u8*)(ws + OFF_B);
  float* part = (float*)(ws + OFF_P);
  float* lraw = (float*)(ws + OFF_LR);
  float* out  = (float*)d_out;

  castAB<<<12160, 256, 0, stream>>>(hs, W, (u32*)Aq, Bq, out);
  gemm_fp8<<<dim3(N_P / 128, M_P / 128), 256, 0, stream>>>(Aq, Bq, bias, ys,
                                                           part, lraw);
  ctc_dp<<<B_N, 512, 0, stream>>>(part, lraw, ys, ilens, olens, out);
}

// Round 14
// 232.683 us; speedup vs baseline: 2.8069x; 2.8069x over previous
//
#include <hip/hip_runtime.h>

typedef unsigned short u16;
typedef unsigned int u32;
typedef unsigned char u8;
typedef __attribute__((ext_vector_type(4))) int int4v;
typedef __attribute__((ext_vector_type(8))) int int8v;
typedef __attribute__((ext_vector_type(4))) float f32x4;

#define NEG (-1e30f)
#define LN2 0.6931471805599453f
#define INV_LN2 1.4426950408889634f

// Problem sizes
#define B_N 16
#define T_N 500
#define E_N 1024
#define V_N 4000
#define L_N 100
#define M_P 8064     // 63*128 padded rows
#define N_P 4096     // 32*128 padded vocab

// ws layout (bytes)
#define OFF_A   0UL          // fp8 A  [8064][1024]    = 8,257,536
#define OFF_B   8257536UL    // fp8 Bt [4096][1024]    = 4,194,304
#define OFF_C   12451840UL   // bf16 C [8064][4096]    = 66,060,288
#define OFF_P   78512128UL   // f32 partial [8064][64] = 2,064,384 (end ~80.6 MB)

__device__ __forceinline__ u16 f2bf(float f) {
  u32 u = __float_as_uint(f);
  u += 0x7fffu + ((u >> 16) & 1u);   // RNE
  return (u16)(u >> 16);
}
__device__ __forceinline__ float bf2f(u16 h) {
  return __uint_as_float(((u32)h) << 16);
}
__device__ __forceinline__ void gl_lds16(const void* g, void* l) {
  __builtin_amdgcn_global_load_lds((const __attribute__((address_space(1))) void*)g,
                                   (__attribute__((address_space(3))) void*)l, 16, 0, 0);
}
// DPP helpers: ctrl must be an ICE -> template parameter.
template <int CTRL>
__device__ __forceinline__ float dpp_f(float x, float fill) {
  return __int_as_float(__builtin_amdgcn_update_dpp(
      __float_as_int(fill), __float_as_int(x), CTRL, 0xF, 0xF, false));
}
__device__ __forceinline__ float dpp_shr1(float x, float fill) {
  return dpp_f<0x138>(x, fill);   // wf_shr1: lane L <- L-1; lane 0 takes fill
}
// 16-lane-row partial sum: lane 15 of each 16-lane row holds the row total.
__device__ __forceinline__ float row16_sum(float x) {
  x += dpp_f<0x111>(x, 0.f); x += dpp_f<0x112>(x, 0.f);
  x += dpp_f<0x114>(x, 0.f); x += dpp_f<0x118>(x, 0.f);
  return x;
}
// wave max -> valid in lane 63. fill = identity.
__device__ __forceinline__ float wave_max(float x, float fill) {
  x = fmaxf(x, dpp_f<0x111>(x, fill));
  x = fmaxf(x, dpp_f<0x112>(x, fill));
  x = fmaxf(x, dpp_f<0x114>(x, fill));
  x = fmaxf(x, dpp_f<0x118>(x, fill));
  x = fmaxf(x, dpp_f<0x142>(x, fill));   // row_bcast:15
  x = fmaxf(x, dpp_f<0x143>(x, fill));   // row_bcast:31
  return x;
}
// wave sum -> valid in lane 63.
__device__ __forceinline__ float wave_sum(float x) {
  x += dpp_f<0x111>(x, 0.f); x += dpp_f<0x112>(x, 0.f);
  x += dpp_f<0x114>(x, 0.f); x += dpp_f<0x118>(x, 0.f);
  x += dpp_f<0x142>(x, 0.f); x += dpp_f<0x143>(x, 0.f);
  return x;
}

// K1: fused input casts. Blocks [0,8064): hs f32 -> fp8 A (pad rows 0), zero d_out.
// Blocks [8064,12160): W transpose-cast -> fp8 Bt, pre-scaled x64.
__global__ __launch_bounds__(256) void castAB(const float* __restrict__ hs,
                                              const float* __restrict__ W,
                                              u32* __restrict__ Aq,
                                              u8* __restrict__ Bq,
                                              float* __restrict__ out) {
  __shared__ float tile[32][33];
  if (blockIdx.x < 8064) {
    int idx = blockIdx.x * 256 + threadIdx.x;   // float4 groups
    if (idx == 0) out[0] = 0.f;
    int row = idx >> 8;
    float4 x;
    if (row < B_N * T_N) x = ((const float4*)hs)[idx];
    else x = make_float4(0.f, 0.f, 0.f, 0.f);
    u32 p = __builtin_amdgcn_cvt_pk_fp8_f32(x.x, x.y, 0, false);
    p = __builtin_amdgcn_cvt_pk_fp8_f32(x.z, x.w, p, true);
    Aq[idx] = p;
  } else {
    int bid = blockIdx.x - 8064;                // 0..4095 = (128 N) x (32 E)
    int v0 = (bid & 127) * 32;
    int e0 = (bid >> 7) * 32;
    int tx = threadIdx.x & 31, ty = threadIdx.x >> 5;
#pragma unroll
    for (int i = 0; i < 4; ++i) {
      int e = e0 + ty * 4 + i;
      int v = v0 + tx;
      tile[ty * 4 + i][tx] = (v < V_N) ? W[e * V_N + v] : 0.f;
    }
    __syncthreads();
#pragma unroll
    for (int i = 0; i < 4; ++i) {
      int vloc = ty * 4 + i;
      float x = tile[tx][vloc] * 64.f;
      u32 p = __builtin_amdgcn_cvt_pk_fp8_f32(x, x, 0, false);
      Bq[(size_t)(v0 + vloc) * 1024 + (e0 + tx)] = (u8)(p & 0xff);
    }
  }
}

// K2: R8-proven MX-fp8 GEMM (VGPR 92, 50.8 us, MfmaUtil 25.7% at (256,2))
// + ONLY the static-indexed partial-sum epilogue (~+12 regs). C is written
// bf16 (raw logits, no bias); partial[row][slice] = sum exp2((z+b)/ln2) over
// the wave's 64 cols. Label gather deliberately NOT fused (R10-R13: every
// gather variant blew the register budget or occupancy).
__global__ __launch_bounds__(256, 2) void gemm_fp8(const u8* __restrict__ A,
                                                   const u8* __restrict__ Bq,
                                                   const float* __restrict__ bias,
                                                   u16* __restrict__ C,
                                                   float* __restrict__ partial) {
  __shared__ __align__(16) u8 As[16 * 1056];
  __shared__ __align__(16) u8 Bs[16 * 1056];
  const int tid = threadIdx.x;
  const int lane = tid & 63;
  const int w = tid >> 6;          // wave 0..3
  const int wm = w >> 1, wn = w & 1;
  const size_t m0 = (size_t)blockIdx.y * 128;
  const size_t n0 = (size_t)blockIdx.x * 128;

  const int lr = lane >> 3;        // row in 8-row group
  const int lc = lane & 7;         // LDS slot
  const int gc = lc ^ lr;          // XOR-swizzled global chunk
  const u8* gA = A + (m0 + w * 32 + lr) * 1024 + gc * 16;
  const u8* gB = Bq + (n0 + w * 32 + lr) * 1024 + gc * 16;
  u8* sA = As + (w * 4) * 1056;
  u8* sB = Bs + (w * 4) * 1056;

  f32x4 acc[4][4];
#pragma unroll
  for (int i = 0; i < 4; ++i)
#pragma unroll
    for (int j = 0; j < 4; ++j) acc[i][j] = (f32x4){0.f, 0.f, 0.f, 0.f};

  const int fr = lane & 15, q = lane >> 4;
  const int c0 = ((2 * q) ^ (fr & 7)) * 16;
  const int c1 = ((2 * q + 1) ^ (fr & 7)) * 16;
  const int rA0 = wm * 64 + fr;
  const int rB0 = wn * 64 + fr;

  for (int kt = 0; kt < 1024; kt += 128) {
#pragma unroll
    for (int u = 0; u < 4; ++u) {
      gl_lds16(gA + (size_t)u * 8192 + kt, sA + u * 1056);
      gl_lds16(gB + (size_t)u * 8192 + kt, sB + u * 1056);
    }
    __syncthreads();
    int8v af[4], bf[4];
#pragma unroll
    for (int i = 0; i < 4; ++i) {
      int r = rA0 + i * 16;
      const u8* p = As + (r >> 3) * 1056 + (r & 7) * 128;
      int4v lo = *(const int4v*)(p + c0);
      int4v hi = *(const int4v*)(p + c1);
      af[i] = (int8v){lo[0], lo[1], lo[2], lo[3], hi[0], hi[1], hi[2], hi[3]};
    }
#pragma unroll
    for (int j = 0; j < 4; ++j) {
      int r = rB0 + j * 16;
      const u8* p = Bs + (r >> 3) * 1056 + (r & 7) * 128;
      int4v lo = *(const int4v*)(p + c0);
      int4v hi = *(const int4v*)(p + c1);
      bf[j] = (int8v){lo[0], lo[1], lo[2], lo[3], hi[0], hi[1], hi[2], hi[3]};
    }
#pragma unroll
    for (int i = 0; i < 4; ++i)
#pragma unroll
      for (int j = 0; j < 4; ++j)
        acc[i][j] = __builtin_amdgcn_mfma_scale_f32_16x16x128_f8f6f4(
            af[i], bf[j], acc[i][j], 0, 0,
            0, 0x7F7F7F7F, 0, 0x7F7F7F7F);   // E8M0 127 = 2^0
    __syncthreads();
  }

  // C/D: col=lane&15, row=(lane>>4)*4+reg; undo W x64 pre-scale (raw logits)
  const int cq = lane >> 4, cc = lane & 15;
#pragma unroll
  for (int i = 0; i < 4; ++i)
#pragma unroll
    for (int j = 0; j < 4; ++j) {
      size_t rr = m0 + wm * 64 + i * 16 + cq * 4;
      size_t nn = n0 + wn * 64 + j * 16 + cc;
      u16* o = C + rr * N_P + nn;
#pragma unroll
      for (int g = 0; g < 4; ++g) o[(size_t)g * N_P] = f2bf(acc[i][j][g] * 0.015625f);
    }

  // epilogue-a (static indexing, R10-logic-verified): per-row exp2 sums
  const float K1C = 0.015625f * INV_LN2;   // undo W x64, to log2 domain
  float k2j[4];
#pragma unroll
  for (int j = 0; j < 4; ++j) {
    int col = (int)n0 + wn * 64 + j * 16 + cc;
    k2j[j] = (col < V_N) ? bias[col] * INV_LN2 : -1e38f;   // pad col -> exp2 = 0
  }
#pragma unroll
  for (int i = 0; i < 4; ++i) {
    float sred[4];
#pragma unroll
    for (int g = 0; g < 4; ++g) {
      float e0 = exp2f(acc[i][0][g] * K1C + k2j[0]);
      float e1 = exp2f(acc[i][1][g] * K1C + k2j[1]);
      float e2 = exp2f(acc[i][2][g] * K1C + k2j[2]);
      float e3 = exp2f(acc[i][3][g] * K1C + k2j[3]);
      sred[g] = row16_sum((e0 + e1) + (e2 + e3));   // lane cc==15 holds row sum
    }
    if (cc == 15) {
#pragma unroll
      for (int g = 0; g < 4; ++g) {
        int row = (int)m0 + wm * 64 + i * 16 + cq * 4 + g;
        partial[(size_t)row * 64 + blockIdx.x * 2 + wn] = sred[g];
      }
    }
  }
}

// K3: finalize + CTC DP (16 blocks x 512 threads = 8 waves).
// Phase A (all waves): per row t, lse2 = log2(wave-sum of 64 slice-partials);
// gather the 101 label logits DIRECTLY from C (scattered bf16, ~3 MB total),
// max-normalize, exp2 -> linear P' tables in LDS. Phase B (wave 0): the
// verified linear-domain scaled-forward DP.
__global__ __launch_bounds__(512) void finalize_dp(const float* __restrict__ partial,
                                                   const u16* __restrict__ C,
                                                   const float* __restrict__ bias,
                                                   const int* __restrict__ ys,
                                                   const int* __restrict__ ilens,
                                                   const int* __restrict__ olens,
                                                   float* __restrict__ out) {
  __shared__ __align__(16) u32 sP[500 * 64];   // 128000 B pair table
  __shared__ float sPB[512];
  __shared__ float sCT[512];
  __shared__ int extL[104];
  __shared__ float biasL[104];
  __shared__ float tmp[8][128];
  int b = blockIdx.x;
  int tid = threadIdx.x;
  int w = tid >> 6, L = tid & 63;

  if (tid < 101) {
    int v = (tid == 0) ? 0 : max(ys[b * L_N + tid - 1], 0);
    extL[tid] = v;
    biasL[tid] = bias[v] * INV_LN2;
  }
  __syncthreads();

  const float* pbase = partial + (size_t)b * 500 * 64;
  const u16* Cb = C + (size_t)b * 500 * N_P;
  int v1 = extL[L];
  int v2 = (L < 37) ? extL[64 + L] : 0;
  float ba1 = biasL[L];
  float ba2 = (L < 37) ? biasL[64 + L] : 0.f;
  for (int t = w; t < T_N; t += 8) {
    float S = wave_sum(pbase[t * 64 + L]);
    float lse2 = __log2f(__int_as_float(
        __builtin_amdgcn_readlane(__float_as_int(S), 63)));
    const u16* Crow = Cb + (size_t)t * N_P;
    float za = bf2f(Crow[v1]) * INV_LN2 + ba1 - lse2;                    // s = L
    float zb = (L < 37) ? bf2f(Crow[v2]) * INV_LN2 + ba2 - lse2 : NEG;   // s = 64+L
    float m = wave_max(fmaxf(za, zb), NEG);
    float c = __int_as_float(__builtin_amdgcn_readlane(__float_as_int(m), 63));
    float pa = exp2f(za - c);
    float pb = (L < 37) ? exp2f(zb - c) : 0.f;
    tmp[w][L] = pa;
    if (L < 40) tmp[w][64 + L] = pb;     // s=101..103 get 0
    asm volatile("s_waitcnt lgkmcnt(0)" ::: "memory");   // in-wave LDS transpose
    float p0 = (L < 50) ? tmp[w][1 + 2 * L] : 0.f;
    float p1 = (L < 50) ? tmp[w][2 + 2 * L] : 0.f;
    sP[t * 64 + L] = ((u32)f2bf(p1) << 16) | (u32)f2bf(p0);
    if (L == 0) { sPB[t] = tmp[w][0]; sCT[t] = c; }
  }
  __syncthreads();
  if (w != 0) return;

  // ---- Phase B: DP (wave 0 only; verified R9..R13) ----
  int k0 = 2 * L, k1 = 2 * L + 1;
  int y0 = extL[1 + min(k0, L_N - 1)];
  int y1 = extL[1 + min(k1, L_N - 1)];
  int y0m = (k0 > 0) ? extL[1 + min(k0 - 1, L_N - 1)] : -1;
  bool allow1 = (y0 != 0) && (y0 != y0m);
  bool allow3 = (y1 != 0) && (y1 != y0);
  int il = ilens[b];   // >= 250

  float a0 = 0.f, a1 = 0.f, a2 = 0.f, a3 = 0.f;
  {
    float pb0 = sPB[0];
    float a1v = bf2f((u16)(sP[0] & 0xffffu));
    if (L == 0) { a0 = pb0; a1 = a1v; }
  }
  int accE = 0;

  u32 curP[8]; float curB[8];
#pragma unroll
  for (int u = 0; u < 8; ++u) {
    curP[u] = sP[(1 + u) * 64 + L];
    curB[u] = sPB[1 + u];
  }
  for (int t0 = 1; t0 < il; t0 += 8) {
    u32 nP[8]; float nB[8];
#pragma unroll
    for (int u = 0; u < 8; ++u) {
      int tn = min(t0 + 8 + u, T_N - 1);
      nP[u] = sP[tn * 64 + L];
      nB[u] = sPB[tn];
    }
#pragma unroll
    for (int u = 0; u < 8; ++u) {
      int t = t0 + u;
      float pk0 = __uint_as_float((curP[u] & 0xffffu) << 16);
      float pk1 = __uint_as_float(curP[u] & 0xffff0000u);
      float p3 = dpp_shr1(a3, 0.f);
      float p3m = allow1 ? p3 : 0.f;
      float a1m = allow3 ? a1 : 0.f;
      float n0 = (a0 + p3) * curB[u];
      float n1 = (a1 + a0 + p3m) * pk0;
      float n2 = (a2 + a1) * curB[u];
      float n3 = (a3 + a2 + a1m) * pk1;
      bool live = t < il;
      a0 = live ? n0 : a0; a1 = live ? n1 : a1;
      a2 = live ? n2 : a2; a3 = live ? n3 : a3;
    }
    float m = fmaxf(fmaxf(a0, a1), fmaxf(a2, a3));
    m = wave_max(m, 0.f);
    u32 mb = (u32)__builtin_amdgcn_readlane(__float_as_int(m), 63);
    int ex = (int)((mb >> 23) & 0xffu);
    ex = (ex < 1) ? 1 : ex;
    float scale = __uint_as_float((u32)(254 - ex) << 23);   // 2^(127-ex)
    a0 *= scale; a1 *= scale; a2 *= scale; a3 *= scale;
    accE += ex - 127;
#pragma unroll
    for (int u = 0; u < 8; ++u) { curP[u] = nP[u]; curB[u] = nB[u]; }
  }

  float cs = 0.f;
#pragma unroll
  for (int i = 0; i < 8; ++i) {
    int t = L + 64 * i;
    cs += (t < il) ? sCT[t] : 0.f;
  }
  cs = wave_sum(cs);
  float csum = __int_as_float(__builtin_amdgcn_readlane(__float_as_int(cs), 63));

  int ol = olens[b];
  int s1 = 2 * ol, s2 = 2 * ol - 1;
  int j1 = s1 & 3, j2 = s2 & 3;
  float t1 = (j1 == 0) ? a0 : a2;
  float t2 = (j2 == 1) ? a1 : a3;
  float x1 = __shfl(t1, s1 >> 2);
  float x2 = __shfl(t2, s2 >> 2);
  float ll2 = __log2f(x1 + x2) + (float)accE + csum;
  if (L == 0) atomicAdd(out, -ll2 * LN2 * (1.0f / B_N));
}

extern "C" void kernel_launch(void* const* d_in, const int* in_sizes, int n_in,
                              void* d_out, int out_size, void* d_ws, size_t ws_size,
                              hipStream_t stream) {
  const float* hs    = (const float*)d_in[0];
  const float* W     = (const float*)d_in[1];
  const float* bias  = (const float*)d_in[2];
  const int*   ys    = (const int*)d_in[3];
  const int*   ilens = (const int*)d_in[4];
  const int*   olens = (const int*)d_in[5];
  char* ws = (char*)d_ws;
  u8*    Aq   = (u8*)(ws + OFF_A);
  u8*    Bq   = (u8*)(ws + OFF_B);
  u16*   Cm   = (u16*)(ws + OFF_C);
  float* part = (float*)(ws + OFF_P);
  float* out  = (float*)d_out;

  castAB<<<12160, 256, 0, stream>>>(hs, W, (u32*)Aq, Bq, out);
  gemm_fp8<<<dim3(N_P / 128, M_P / 128), 256, 0, stream>>>(Aq, Bq, bias, Cm, part);
  finalize_dp<<<B_N, 512, 0, stream>>>(part, Cm, bias, ys, ilens, olens, out);
}